// Round 8
// baseline (361.770 us; speedup 1.0000x reference)
//
#include <hip/hip_runtime.h>
#include <math.h>

// Sizes fixed by the problem.
#define N_AG   512
#define HIDD   256
#define OBSD   128
// P = 512*511/2 = 130816 pairs, out = [P,3]

#define NBLK   512u

typedef float f32x4_t __attribute__((ext_vector_type(4)));
typedef int   i32x4_t __attribute__((ext_vector_type(4)));

// CK-style raw buffer load intrinsic (compiler handles waitcnt/scheduling).
__device__ f32x4_t llvm_amdgcn_raw_buffer_load_v4f32(i32x4_t srsrc, int voffset,
        int soffset, int cpol) __asm("llvm.amdgcn.raw.buffer.load.v4f32");

// cpol = GLC|SLC|SCC = 1|2|16 -> emits "sc0 nt sc1" on gfx950:
// full streaming policy — bypass L1+L2, NO MALL(IF) allocation. This is the fix for
// the 135MB/iter of dirty ws-poison evictions our stream reads were forcing out of IF.
#define CPOL_STREAM 19

__device__ __forceinline__ i32x4_t make_srsrc(const void* ptr, unsigned bytes){
    union { i32x4_t v; struct { unsigned lo, hi, rec, cfg; } s; } u;
    unsigned long long a = (unsigned long long)ptr;
    u.s.lo  = (unsigned)a;
    u.s.hi  = (unsigned)(a >> 32);   // VA<2^48, stride bits [29:16] stay 0
    u.s.rec = bytes;                 // num_records (bytes, stride==0)
    u.s.cfg = 0x00020000;            // raw untyped dword access
    return u.v;
}

__device__ __forceinline__ void fma4(float4& acc, float4 a, float4 b){
    acc.x += a.x*b.x; acc.y += a.y*b.y; acc.z += a.z*b.z; acc.w += a.w*b.w;
}
__device__ __forceinline__ void fma4v(float4& acc, float4 a, f32x4_t b){
    acc.x += a.x*b.x; acc.y += a.y*b.y; acc.z += a.z*b.z; acc.w += a.w*b.w;
}
__device__ __forceinline__ float hsum(float4 a){ return (a.x+a.y)+(a.z+a.w); }

// ---- agent-scope write-through stores (sc1): producers' inter-stage data goes straight
// to the device coherence point -> no dirty per-XCD L2 lines -> no wbl2/inv fences. ----
__device__ __forceinline__ void st1_sc1(float* p, float v){
    asm volatile("global_store_dword %0, %1, off sc1" :: "v"(p), "v"(v) : "memory");
}
__device__ __forceinline__ void st4_sc1(float* p, float4 v){
    f32x4_t w; w.x = v.x; w.y = v.y; w.z = v.z; w.w = v.w;
    asm volatile("global_store_dwordx4 %0, %1, off sc1" :: "v"(p), "v"(w) : "memory");
}

// ---- hierarchical fence-free grid barrier (round-7: cut barrier cost 281->189us) ----
// arrive[g] (8 lines): 64 adds each, polled by 1 leader; global word: 8 leaders;
// grel[g]: 63 pollers @ s_sleep(32). Residency: 2 blocks/CU by launch bounds, grid=512.
// Word layout in sync[]: [0]=global; [64+g*64]=arrive[g]; [576+g*64]=grel[g]; [1088+g]=claim[g]
__device__ __forceinline__ void grid_barrier(unsigned* sync, unsigned round, int bid){
    asm volatile("s_waitcnt vmcnt(0)" ::: "memory");   // drain asm sc1 stores
    __syncthreads();
    if (threadIdx.x == 0){
        int g = bid & 7;
        unsigned* arrive = sync + 64  + g*64;
        unsigned* grel   = sync + 576 + g*64;
        __hip_atomic_fetch_add(arrive, 1u, __ATOMIC_RELAXED, __HIP_MEMORY_SCOPE_AGENT);
        if (bid < 8){   // leader of group g==bid
            while (__hip_atomic_load(arrive, __ATOMIC_RELAXED, __HIP_MEMORY_SCOPE_AGENT) < 64u*round)
                __builtin_amdgcn_s_sleep(4);
            __hip_atomic_fetch_add(sync, 1u, __ATOMIC_RELAXED, __HIP_MEMORY_SCOPE_AGENT);
            while (__hip_atomic_load(sync, __ATOMIC_RELAXED, __HIP_MEMORY_SCOPE_AGENT) < 8u*round)
                __builtin_amdgcn_s_sleep(4);
            __hip_atomic_store(grel, round, __ATOMIC_RELAXED, __HIP_MEMORY_SCOPE_AGENT);
        } else {
            while (__hip_atomic_load(grel, __ATOMIC_RELAXED, __HIP_MEMORY_SCOPE_AGENT) < round)
                __builtin_amdgcn_s_sleep(32);
        }
    }
    __syncthreads();
}

// ---- shared GEMM-tile helpers: 64x64 output tile, K-chunks of 32, LDS [32][68] kk-major ----
__device__ __forceinline__ void stage_rows(float* dst, const float* __restrict__ src,
        int row0, int stride, int colbase, int t){
    #pragma unroll
    for (int half = 0; half < 2; ++half){
        int idx = half*256 + t;
        int row = idx >> 3, c4 = idx & 7;
        float4 v = *(const float4*)(src + (row0+row)*stride + colbase + c4*4);
        dst[(c4*4+0)*68 + row] = v.x;
        dst[(c4*4+1)*68 + row] = v.y;
        dst[(c4*4+2)*68 + row] = v.z;
        dst[(c4*4+3)*68 + row] = v.w;
    }
}
__device__ __forceinline__ void tile_compute(const float* As, const float* Bs,
        int tx, int ty, float4 acc[4]){
    #pragma unroll
    for (int kk = 0; kk < 32; ++kk){
        float4 a = *(const float4*)(As + kk*68 + ty*4);
        float4 b = *(const float4*)(Bs + kk*68 + tx*4);
        acc[0].x += a.x*b.x; acc[0].y += a.x*b.y; acc[0].z += a.x*b.z; acc[0].w += a.x*b.w;
        acc[1].x += a.y*b.x; acc[1].y += a.y*b.y; acc[1].z += a.y*b.z; acc[1].w += a.y*b.w;
        acc[2].x += a.z*b.x; acc[2].y += a.z*b.y; acc[2].z += a.z*b.z; acc[2].w += a.z*b.w;
        acc[3].x += a.w*b.x; acc[3].y += a.w*b.y; acc[3].z += a.w*b.z; acc[3].w += a.w*b.w;
    }
}

// ---- one 64KB chunk of one vfc2_w row, dot with flattened hid ----
// vfc2_w loads: buffer_load sc0 nt sc1 (full cache bypass). hid loads: cached (128x reuse).
__device__ __forceinline__ void stream_unit(int u, const float* __restrict__ hid,
        i32x4_t vsrsrc, float* __restrict__ partial, float* red, int t){
    int chunk = u & 7, o = u >> 3;
    const float4* h4 = (const float4*)hid;
    long base  = (long)chunk*4096;                 // float4 units
    long wbase = (long)o*32768 + base;
    unsigned wb = ((unsigned)wbase + (unsigned)t) * 16u;   // byte offset, <134MB
    float4 aa = {0,0,0,0}, ab = {0,0,0,0};
    #pragma unroll 4
    for (int it = 0; it < 8; ++it){    // two interleaved streams -> 2x load ILP
        f32x4_t wa = llvm_amdgcn_raw_buffer_load_v4f32(vsrsrc, (int)(wb + it*4096u),     0, CPOL_STREAM);
        f32x4_t wv = llvm_amdgcn_raw_buffer_load_v4f32(vsrsrc, (int)(wb + (it+8)*4096u), 0, CPOL_STREAM);
        fma4v(aa, h4[base + it*256 + t],     wa);
        fma4v(ab, h4[base + (it+8)*256 + t], wv);
    }
    float acc = hsum(aa) + hsum(ab);
    for (int off = 32; off; off >>= 1) acc += __shfl_xor(acc, off);
    int lane = t & 63, wid = t >> 6;
    if (lane == 0) red[wid] = acc;
    __syncthreads();
    if (t == 0) st1_sc1(partial + o*8 + chunk, red[0]+red[1]+red[2]+red[3]);
}

// =====================================================================================
// One kernel, 512 blocks x 256 threads, 5 stages / 4 hierarchical grid barriers.
//  entry: 1 buffer_inv per XCD (clears pre-kernel clean poison lines)
//  S0: fc1+qkv (128 agent-groups x 4 out-quarters)       [hid,qkv stored sc1]
//  S1: score tiles(64) | VW tiles(32) | vfc2 stream 0..1023 (96..511)   [S,VW,partial sc1]
//  S2: h tiles w/ fused softmax (64) | stream 1024..2047 (64..511)      [h,partial sc1]
//  S3: A/B (512) + value finish (block 511)              [A,B,value sc1]
//  S4: pairs, 528 triangular tiles over 512 blocks       [out plain; end-of-dispatch flush]
// =====================================================================================
__global__ __launch_bounds__(256, 2) void k_mega(
        const float* __restrict__ in,
        const float* __restrict__ fc1w, const float* __restrict__ fc1b,
        const float* __restrict__ ipw,  const float* __restrict__ ipb,
        const float* __restrict__ opw,  const float* __restrict__ opb,
        const float* __restrict__ fc2w, const float* __restrict__ fc2b,
        const float* __restrict__ fc3w, const float* __restrict__ fc3b,
        const float* __restrict__ vw2,  const float* __restrict__ vb2,
        const float* __restrict__ vw3,  const float* __restrict__ vb3,
        float* __restrict__ hid, float* __restrict__ qkv, float* __restrict__ S,
        float* __restrict__ VW, float* __restrict__ h,
        float* __restrict__ A, float* __restrict__ B,
        float* __restrict__ partial, float* __restrict__ value,
        float* __restrict__ out, unsigned* __restrict__ sync)
{
    __shared__ float smem[8704];       // 34 KB: max of all stage footprints
    int bid = blockIdx.x, t = threadIdx.x;

    // ---------------- entry: per-XCD L2 invalidate (one leader per XCD) ----------------
    if (t == 0){
        unsigned xcc;
        asm volatile("s_getreg_b32 %0, hwreg(HW_REG_XCC_ID)" : "=s"(xcc));
        if (__hip_atomic_fetch_add(sync + 1088 + (xcc & 7u), 1u, __ATOMIC_RELAXED,
                                   __HIP_MEMORY_SCOPE_AGENT) == 0u)
            asm volatile("buffer_inv sc1" ::: "memory");
    }

    i32x4_t vsrsrc = make_srsrc(vw2, 256u*131072u*4u);   // 134,217,728 bytes

    // ---------------- Stage 0: embed (fc1 + qkv) ----------------
    {
        int grp = bid >> 2, quarter = bid & 3;
        int a0 = grp*4;
        float* lin  = smem;            // 4*128
        float* hidL = smem + 512;      // 4*256
        if (t < 128) ((float4*)lin)[t] = ((const float4*)(in + a0*OBSD))[t];
        __syncthreads();
        {   // hid for 4 agents, thread owns column o = t (recomputed by all 4 quarters)
            int o = t;
            const float4* w4 = (const float4*)(fc1w + o*OBSD);
            const float4* l4 = (const float4*)lin;
            float4 acc[4] = {{0,0,0,0},{0,0,0,0},{0,0,0,0},{0,0,0,0}};
            #pragma unroll
            for (int c = 0; c < OBSD/4; ++c){
                float4 wv = w4[c];
                #pragma unroll
                for (int g = 0; g < 4; ++g) fma4(acc[g], l4[g*32 + c], wv);
            }
            float bb = fc1b[o];
            #pragma unroll
            for (int g = 0; g < 4; ++g){
                float v = fmaxf(hsum(acc[g]) + bb, 0.f);
                hidL[g*HIDD + o] = v;
                if (quarter == 0) st1_sc1(&hid[(a0+g)*HIDD + o], v);
            }
        }
        __syncthreads();
        // qkv: this block covers outs [quarter*192, quarter*192+192) for 4 agents
        const float4* hl4 = (const float4*)hidL;
        #pragma unroll
        for (int r = 0; r < 3; ++r){
            int idx = r*256 + t;                  // 0..767
            int g = idx / 192, oo = idx - g*192;
            int o = quarter*192 + oo;
            const float4* w4 = (const float4*)(ipw + o*HIDD);
            float4 acc = {0,0,0,0};
            #pragma unroll 8
            for (int c = 0; c < HIDD/4; ++c) fma4(acc, hl4[g*64 + c], w4[c]);
            st1_sc1(&qkv[(a0+g)*768 + o], hsum(acc) + ipb[o]);
        }
    }
    grid_barrier(sync, 1u, bid);

    // ---------------- Stage 1: scores | VW | stream 0..1023 ----------------
    {
        float* As = smem;              // 32*68
        float* Bs = smem + 2176;       // 32*68
        if (bid < 64){
            int ti = bid >> 3, tj = bid & 7;
            int i0 = ti*64, j0 = tj*64;
            int tx = t & 15, ty = t >> 4;
            float4 acc[4] = {{0,0,0,0},{0,0,0,0},{0,0,0,0},{0,0,0,0}};
            for (int k0 = 0; k0 < 256; k0 += 32){
                __syncthreads();
                stage_rows(As, qkv, i0, 768, k0,       t);   // Q chunk
                stage_rows(Bs, qkv, j0, 768, 256 + k0, t);   // K chunk
                __syncthreads();
                tile_compute(As, Bs, tx, ty, acc);
            }
            #pragma unroll
            for (int r = 0; r < 4; ++r){
                float4 o;
                o.x = acc[r].x*0.0625f; o.y = acc[r].y*0.0625f;
                o.z = acc[r].z*0.0625f; o.w = acc[r].w*0.0625f;
                st4_sc1(S + (i0+ty*4+r)*512 + j0 + tx*4, o);
            }
        } else if (bid < 96){
            int b2 = bid - 64;
            int ti = b2 >> 2, tj = b2 & 3;
            int j0 = ti*64, d0 = tj*64;
            int tx = t & 15, ty = t >> 4;
            float4 acc[4] = {{0,0,0,0},{0,0,0,0},{0,0,0,0},{0,0,0,0}};
            for (int k0 = 0; k0 < 256; k0 += 32){
                __syncthreads();
                stage_rows(As, qkv, j0, 768, 512 + k0, t);   // V chunk
                stage_rows(Bs, opw, d0, 256, k0,       t);   // ow chunk
                __syncthreads();
                tile_compute(As, Bs, tx, ty, acc);
            }
            #pragma unroll
            for (int r = 0; r < 4; ++r)
                st4_sc1(VW + (j0+ty*4+r)*256 + d0 + tx*4, acc[r]);
        } else {
            for (int u = bid - 96; u < 1024; u += 416){
                __syncthreads();
                stream_unit(u, hid, vsrsrc, partial, smem + 4352, t);
            }
        }
    }
    grid_barrier(sync, 2u, bid);

    // ---------------- Stage 2: h = softmax(S) @ VW + ob  |  stream 1024..2047 ----------------
    {
        if (bid < 64){
            int ti = bid >> 2, tj = bid & 3;     // 16 i-tiles of 32 rows, 4 d-tiles of 64
            int i0 = ti*32, d0 = tj*64;
            float* As   = smem;                  // 32*68
            float* Bs   = smem + 2176;           // 32*68
            float* rowm = smem + 4352;           // 32
            float* rowi = smem + 4384;           // 32
            {   // per-block softmax stats for rows i0..i0+31 (8 threads per row)
                int r = t >> 3, c8 = t & 7;
                const float4* Sr = (const float4*)(S + (i0 + r)*512);
                float m = -1e30f;
                #pragma unroll
                for (int k = 0; k < 16; ++k){
                    float4 v = Sr[c8 + k*8];
                    m = fmaxf(m, fmaxf(fmaxf(v.x, v.y), fmaxf(v.z, v.w)));
                }
                m = fmaxf(m, __shfl_xor(m, 1));
                m = fmaxf(m, __shfl_xor(m, 2));
                m = fmaxf(m, __shfl_xor(m, 4));
                float s = 0.f;
                #pragma unroll
                for (int k = 0; k < 16; ++k){
                    float4 v = Sr[c8 + k*8];
                    s += expf(v.x-m) + expf(v.y-m) + expf(v.z-m) + expf(v.w-m);
                }
                s += __shfl_xor(s, 1); s += __shfl_xor(s, 2); s += __shfl_xor(s, 4);
                if (c8 == 0){ rowm[r] = m; rowi[r] = 1.f/s; }
            }
            __syncthreads();
            int tx = t & 15, ty = t >> 4;        // 16 row-pairs x 16 col-quads
            float4 acc0 = {0,0,0,0}, acc1 = {0,0,0,0};
            for (int k0 = 0; k0 < 512; k0 += 32){
                __syncthreads();
                {   // stage P chunk with exp applied on the fly (identical math to old path)
                    int row = t >> 3, c4 = t & 7;
                    float m = rowm[row], iv = rowi[row];
                    float4 v = *(const float4*)(S + (i0+row)*512 + k0 + c4*4);
                    As[(c4*4+0)*68 + row] = expf(v.x - m)*iv;
                    As[(c4*4+1)*68 + row] = expf(v.y - m)*iv;
                    As[(c4*4+2)*68 + row] = expf(v.z - m)*iv;
                    As[(c4*4+3)*68 + row] = expf(v.w - m)*iv;
                }
                #pragma unroll
                for (int half = 0; half < 2; ++half){
                    int idx = half*256 + t;
                    int kkr = idx >> 4, c4 = idx & 15;
                    *(float4*)(Bs + kkr*68 + c4*4) = *(const float4*)(VW + (k0+kkr)*256 + d0 + c4*4);
                }
                __syncthreads();
                #pragma unroll
                for (int kk = 0; kk < 32; ++kk){
                    float2 a = *(const float2*)(As + kk*68 + ty*2);
                    float4 b = *(const float4*)(Bs + kk*68 + tx*4);
                    acc0.x += a.x*b.x; acc0.y += a.x*b.y; acc0.z += a.x*b.z; acc0.w += a.x*b.w;
                    acc1.x += a.y*b.x; acc1.y += a.y*b.y; acc1.z += a.y*b.z; acc1.w += a.y*b.w;
                }
            }
            float4 bb = *(const float4*)(opb + d0 + tx*4);
            float4 o0, o1;
            o0.x = acc0.x+bb.x; o0.y = acc0.y+bb.y; o0.z = acc0.z+bb.z; o0.w = acc0.w+bb.w;
            o1.x = acc1.x+bb.x; o1.y = acc1.y+bb.y; o1.z = acc1.z+bb.z; o1.w = acc1.w+bb.w;
            st4_sc1(h + (i0+ty*2  )*256 + d0 + tx*4, o0);
            st4_sc1(h + (i0+ty*2+1)*256 + d0 + tx*4, o1);
        } else {
            for (int u = 1024 + (bid - 64); u < 2048; u += 448){
                __syncthreads();
                stream_unit(u, hid, vsrsrc, partial, smem + 4352, t);
            }
        }
    }
    grid_barrier(sync, 3u, bid);

    // ---------------- Stage 3: A/B projections (all 512) + value finish (block 511) ----------------
    {
        float* lin  = smem;            // 8*256
        float* redv = smem + 2048;     // 4
        if (bid == 511){
            float s = vb2[t];
            #pragma unroll
            for (int c = 0; c < 8; ++c) s += partial[t*8 + c];
            s = fmaxf(s, 0.f) * vw3[t];
            for (int off = 32; off; off >>= 1) s += __shfl_xor(s, off);
            int lane = t & 63, wid = t >> 6;
            if (lane == 0) redv[wid] = s;
            __syncthreads();
            if (t == 0) st1_sc1(value, redv[0]+redv[1]+redv[2]+redv[3] + vb3[0]);
            __syncthreads();
        }
        int at = bid >> 3, ot = bid & 7;
        const float4* in4 = (const float4*)(h + at*8*HIDD);
        ((float4*)lin)[t]       = in4[t];
        ((float4*)lin)[t + 256] = in4[t + 256];
        __syncthreads();
        int ol = t & 63, g = t >> 6;
        int o2 = ot*64 + ol;                   // 0..511
        bool isA = o2 < HIDD;
        int o = isA ? o2 : o2 - HIDD;
        const float4* w4 = (const float4*)(fc2w + o*512 + (isA ? 0 : HIDD));
        const float4* la4 = (const float4*)(lin + (g*2)*HIDD);
        const float4* lb4 = (const float4*)(lin + (g*2+1)*HIDD);
        float4 acc0 = {0,0,0,0}, acc1 = {0,0,0,0};
        #pragma unroll 8
        for (int c = 0; c < HIDD/4; ++c){
            float4 wv = w4[c];
            fma4(acc0, la4[c], wv);
            fma4(acc1, lb4[c], wv);
        }
        int a0 = at*8 + g*2;
        float* dst = isA ? A : B;
        float bb = isA ? fc2b[o] : 0.f;        // fold fc2_b into A
        st1_sc1(&dst[a0*HIDD + o],     hsum(acc0) + bb);
        st1_sc1(&dst[(a0+1)*HIDD + o], hsum(acc1) + bb);
    }
    grid_barrier(sync, 4u, bid);

    // ---------------- Stage 4: pairs, 528 triangular tiles over 512 blocks ----------------
    {
        float* la = smem;              // 16*260
        float* lb = smem + 4160;       // 16*260
        float* lw = smem + 8320;       // 256
        float val = value[0];
        float bd  = fc3b[0] - fc3b[1];
        for (int tile = bid; tile < 528; tile += 512){
            int rem = tile, ti = 0;
            while (rem >= 32 - ti){ rem -= 32 - ti; ++ti; }
            int tj = ti + rem;                 // ti <= tj guaranteed
            __syncthreads();
            #pragma unroll
            for (int l = 0; l < 4; ++l){
                int idx = l*256 + t;
                int r = idx >> 6, c4 = idx & 63;
                ((float4*)la)[r*65 + c4] = ((const float4*)A)[(ti*16 + r)*64 + c4];
                ((float4*)lb)[r*65 + c4] = ((const float4*)B)[(tj*16 + r)*64 + c4];
            }
            lw[t] = fc3w[t] - fc3w[256 + t];   // fc3_w[0]-fc3_w[1]
            __syncthreads();
            int il = t >> 4, jl = t & 15;
            int i = ti*16 + il, j = tj*16 + jl;
            if (j > i){
                const float4* a4 = (const float4*)(la + il*260);
                const float4* b4 = (const float4*)(lb + jl*260);
                const float4* w4 = (const float4*)lw;
                float4 acc = {0,0,0,0};
                #pragma unroll 8
                for (int c = 0; c < 64; ++c){
                    float4 aa = a4[c], bb = b4[c], wv = w4[c];
                    acc.x += fmaxf(aa.x + bb.x, 0.f)*wv.x;
                    acc.y += fmaxf(aa.y + bb.y, 0.f)*wv.y;
                    acc.z += fmaxf(aa.z + bb.z, 0.f)*wv.z;
                    acc.w += fmaxf(aa.w + bb.w, 0.f)*wv.w;
                }
                float z = hsum(acc) + bd;
                float o0 = 1.f/(1.f + expf(-z));
                int p = i*511 - (i*(i-1))/2 + (j - i - 1);
                out[3*p]   = o0;
                out[3*p+1] = 1.f - o0;
                out[3*p+2] = val;
            }
        }
    }
}

extern "C" void kernel_launch(void* const* d_in, const int* in_sizes, int n_in,
                              void* d_out, int out_size, void* d_ws, size_t ws_size,
                              hipStream_t stream){
    const float* inputs = (const float*)d_in[0];
    const float* fc1_w  = (const float*)d_in[1];
    const float* fc1_b  = (const float*)d_in[2];
    const float* inp_w  = (const float*)d_in[3];
    const float* inp_b  = (const float*)d_in[4];
    const float* outp_w = (const float*)d_in[5];
    const float* outp_b = (const float*)d_in[6];
    const float* fc2_w  = (const float*)d_in[7];
    const float* fc2_b  = (const float*)d_in[8];
    const float* fc3_w  = (const float*)d_in[9];
    const float* fc3_b  = (const float*)d_in[10];
    const float* vfc2_w = (const float*)d_in[11];
    const float* vfc2_b = (const float*)d_in[12];
    const float* vfc3_w = (const float*)d_in[13];
    const float* vfc3_b = (const float*)d_in[14];
    float* out = (float*)d_out;
    float* ws  = (float*)d_ws;
    // ws layout (floats)
    float* hid     = ws;              // 512*256
    float* qkv     = ws + 131072;     // 512*768
    float* S       = ws + 524288;     // 512*512 (raw scores; softmax fused downstream)
    float* VW      = ws + 786432;     // 512*256
    float* h       = ws + 917504;     // 512*256
    float* A       = ws + 1048576;    // 512*256
    float* B       = ws + 1179648;    // 512*256
    float* partial = ws + 1310720;    // 256*8
    float* value   = ws + 1312768;    // 1
    unsigned* sync = (unsigned*)(ws + 1312832); // hierarchical barrier region (~4.5KB)

    // ws is poisoned between runs: all sync words must start at 0 each replay.
    hipMemsetAsync(sync, 0, 8192, stream);

    k_mega<<<dim3(512), dim3(256), 0, stream>>>(
        inputs, fc1_w, fc1_b, inp_w, inp_b, outp_w, outp_b,
        fc2_w, fc2_b, fc3_w, fc3_b, vfc2_w, vfc2_b, vfc3_w, vfc3_b,
        hid, qkv, S, VW, h, A, B, partial, value, out, sync);
}

// Round 9
// 344.390 us; speedup vs baseline: 1.0505x; 1.0505x over previous
//
#include <hip/hip_runtime.h>
#include <math.h>

// Sizes fixed by the problem.
#define N_AG   512
#define HIDD   256
#define OBSD   128
// P = 512*511/2 = 130816 pairs, out = [P,3]

typedef float f32x4_t __attribute__((ext_vector_type(4)));

__device__ __forceinline__ void fma4(float4& acc, float4 a, float4 b){
    acc.x += a.x*b.x; acc.y += a.y*b.y; acc.z += a.z*b.z; acc.w += a.w*b.w;
}
__device__ __forceinline__ float hsum(float4 a){ return (a.x+a.y)+(a.z+a.w); }

// non-temporal load for the read-once vfc2_w stream (harmless; L2-pollution hint only)
__device__ __forceinline__ float4 ld4_nt(const float4* p){
    f32x4_t v = __builtin_nontemporal_load((const f32x4_t*)p);
    float4 r; r.x = v.x; r.y = v.y; r.z = v.z; r.w = v.w; return r;
}

// ---- shared GEMM-tile helpers: 64x64 output tile, K-chunks of 32, LDS [32][68] kk-major ----
__device__ __forceinline__ void stage_rows(float* dst, const float* __restrict__ src,
        int row0, int stride, int colbase, int t){
    #pragma unroll
    for (int half = 0; half < 2; ++half){
        int idx = half*256 + t;
        int row = idx >> 3, c4 = idx & 7;
        float4 v = *(const float4*)(src + (row0+row)*stride + colbase + c4*4);
        dst[(c4*4+0)*68 + row] = v.x;
        dst[(c4*4+1)*68 + row] = v.y;
        dst[(c4*4+2)*68 + row] = v.z;
        dst[(c4*4+3)*68 + row] = v.w;
    }
}
__device__ __forceinline__ void tile_compute(const float* As, const float* Bs,
        int tx, int ty, float4 acc[4]){
    #pragma unroll
    for (int kk = 0; kk < 32; ++kk){
        float4 a = *(const float4*)(As + kk*68 + ty*4);
        float4 b = *(const float4*)(Bs + kk*68 + tx*4);
        acc[0].x += a.x*b.x; acc[0].y += a.x*b.y; acc[0].z += a.x*b.z; acc[0].w += a.x*b.w;
        acc[1].x += a.y*b.x; acc[1].y += a.y*b.y; acc[1].z += a.y*b.z; acc[1].w += a.y*b.w;
        acc[2].x += a.z*b.x; acc[2].y += a.z*b.y; acc[2].z += a.z*b.z; acc[2].w += a.z*b.w;
        acc[3].x += a.w*b.x; acc[3].y += a.w*b.y; acc[3].z += a.w*b.z; acc[3].w += a.w*b.w;
    }
}

// ---- one 64KB chunk of one vfc2_w row, dot with flattened hid ----
__device__ __forceinline__ void stream_unit(int u, const float* __restrict__ hid,
        const float* __restrict__ vw2, float* __restrict__ partial,
        float* red, int t){
    int chunk = u & 7, o = u >> 3;
    const float4* h4 = (const float4*)hid;
    const float4* w4 = (const float4*)vw2;
    long base  = (long)chunk*4096;     // float4 units
    long wbase = (long)o*32768 + base;
    float4 aa = {0,0,0,0}, ab = {0,0,0,0};
    #pragma unroll 4
    for (int it = 0; it < 8; ++it){    // two interleaved streams -> 2x load ILP
        fma4(aa, h4[base + it*256 + t],     ld4_nt(w4 + wbase + it*256 + t));
        fma4(ab, h4[base + (it+8)*256 + t], ld4_nt(w4 + wbase + (it+8)*256 + t));
    }
    float acc = hsum(aa) + hsum(ab);
    for (int off = 32; off; off >>= 1) acc += __shfl_xor(acc, off);
    int lane = t & 63, wid = t >> 6;
    if (lane == 0) red[wid] = acc;
    __syncthreads();
    if (t == 0) partial[o*8 + chunk] = red[0]+red[1]+red[2]+red[3];
}

// =====================================================================================
// 5 dispatches = the mega-kernel split at its barrier lines. CP dispatch boundaries
// provide sync + coherence (round 2-8: software barriers cost ~30us each, CP ~3-5us).
// Tiles at LOW bids so they schedule first and hide under the stream long-pole.
// =====================================================================================

// ---- K0: fc1+qkv fused. 512 blocks = 128 agent-groups x 4 output-quarters. ----
__global__ __launch_bounds__(256, 2) void k_embed(
        const float* __restrict__ in,
        const float* __restrict__ fc1w, const float* __restrict__ fc1b,
        const float* __restrict__ ipw,  const float* __restrict__ ipb,
        float* __restrict__ hid, float* __restrict__ qkv)
{
    __shared__ float lin[512];         // 4*128
    __shared__ float hidL[1024];       // 4*256
    int bid = blockIdx.x, t = threadIdx.x;
    int grp = bid >> 2, quarter = bid & 3;
    int a0 = grp*4;
    if (t < 128) ((float4*)lin)[t] = ((const float4*)(in + a0*OBSD))[t];
    __syncthreads();
    {   // hid for 4 agents, thread owns column o = t (recomputed by all 4 quarters)
        int o = t;
        const float4* w4 = (const float4*)(fc1w + o*OBSD);
        const float4* l4 = (const float4*)lin;
        float4 acc[4] = {{0,0,0,0},{0,0,0,0},{0,0,0,0},{0,0,0,0}};
        #pragma unroll
        for (int c = 0; c < OBSD/4; ++c){
            float4 wv = w4[c];
            #pragma unroll
            for (int g = 0; g < 4; ++g) fma4(acc[g], l4[g*32 + c], wv);
        }
        float bb = fc1b[o];
        #pragma unroll
        for (int g = 0; g < 4; ++g){
            float v = fmaxf(hsum(acc[g]) + bb, 0.f);
            hidL[g*HIDD + o] = v;
            if (quarter == 0) hid[(a0+g)*HIDD + o] = v;
        }
    }
    __syncthreads();
    // qkv: this block covers outs [quarter*192, quarter*192+192) for 4 agents
    const float4* hl4 = (const float4*)hidL;
    #pragma unroll
    for (int r = 0; r < 3; ++r){
        int idx = r*256 + t;                  // 0..767
        int g = idx / 192, oo = idx - g*192;
        int o = quarter*192 + oo;
        const float4* w4 = (const float4*)(ipw + o*HIDD);
        float4 acc = {0,0,0,0};
        #pragma unroll 8
        for (int c = 0; c < HIDD/4; ++c) fma4(acc, hl4[g*64 + c], w4[c]);
        qkv[(a0+g)*768 + o] = hsum(acc) + ipb[o];
    }
}

// ---- K1: grid 1120. bid<64 score tiles | <96 VW tiles | 96..1119 stream units 0..1023 ----
__global__ __launch_bounds__(256, 2) void k_s1(
        const float* __restrict__ qkv, const float* __restrict__ opw,
        const float* __restrict__ hid, const float* __restrict__ vw2,
        float* __restrict__ S, float* __restrict__ VW, float* __restrict__ partial)
{
    __shared__ float As[2176];
    __shared__ float Bs[2176];
    __shared__ float red[4];
    int bid = blockIdx.x, t = threadIdx.x;
    if (bid < 64){
        int ti = bid >> 3, tj = bid & 7;
        int i0 = ti*64, j0 = tj*64;
        int tx = t & 15, ty = t >> 4;
        float4 acc[4] = {{0,0,0,0},{0,0,0,0},{0,0,0,0},{0,0,0,0}};
        for (int k0 = 0; k0 < 256; k0 += 32){
            __syncthreads();
            stage_rows(As, qkv, i0, 768, k0,       t);   // Q chunk
            stage_rows(Bs, qkv, j0, 768, 256 + k0, t);   // K chunk
            __syncthreads();
            tile_compute(As, Bs, tx, ty, acc);
        }
        #pragma unroll
        for (int r = 0; r < 4; ++r){
            float4 o;
            o.x = acc[r].x*0.0625f; o.y = acc[r].y*0.0625f;
            o.z = acc[r].z*0.0625f; o.w = acc[r].w*0.0625f;
            *(float4*)(S + (i0+ty*4+r)*512 + j0 + tx*4) = o;
        }
    } else if (bid < 96){
        int b2 = bid - 64;
        int ti = b2 >> 2, tj = b2 & 3;
        int j0 = ti*64, d0 = tj*64;
        int tx = t & 15, ty = t >> 4;
        float4 acc[4] = {{0,0,0,0},{0,0,0,0},{0,0,0,0},{0,0,0,0}};
        for (int k0 = 0; k0 < 256; k0 += 32){
            __syncthreads();
            stage_rows(As, qkv, j0, 768, 512 + k0, t);   // V chunk
            stage_rows(Bs, opw, d0, 256, k0,       t);   // ow chunk
            __syncthreads();
            tile_compute(As, Bs, tx, ty, acc);
        }
        #pragma unroll
        for (int r = 0; r < 4; ++r)
            *(float4*)(VW + (j0+ty*4+r)*256 + d0 + tx*4) = acc[r];
    } else {
        stream_unit(bid - 96, hid, vw2, partial, red, t);
    }
}

// ---- K2: grid 1088. bid<64 h-tiles w/ fused softmax | 64..1087 stream units 1024..2047 ----
__global__ __launch_bounds__(256, 2) void k_s2(
        const float* __restrict__ S, const float* __restrict__ VW,
        const float* __restrict__ opb, const float* __restrict__ hid,
        const float* __restrict__ vw2, float* __restrict__ h,
        float* __restrict__ partial)
{
    __shared__ float As[2176];
    __shared__ float Bs[2176];
    __shared__ float rowm[32];
    __shared__ float rowi[32];
    __shared__ float red[4];
    int bid = blockIdx.x, t = threadIdx.x;
    if (bid < 64){
        int ti = bid >> 2, tj = bid & 3;     // 16 i-tiles of 32 rows, 4 d-tiles of 64
        int i0 = ti*32, d0 = tj*64;
        {   // per-block softmax stats for rows i0..i0+31 (8 threads per row)
            int r = t >> 3, c8 = t & 7;
            const float4* Sr = (const float4*)(S + (i0 + r)*512);
            float m = -1e30f;
            #pragma unroll
            for (int k = 0; k < 16; ++k){
                float4 v = Sr[c8 + k*8];
                m = fmaxf(m, fmaxf(fmaxf(v.x, v.y), fmaxf(v.z, v.w)));
            }
            m = fmaxf(m, __shfl_xor(m, 1));
            m = fmaxf(m, __shfl_xor(m, 2));
            m = fmaxf(m, __shfl_xor(m, 4));
            float s = 0.f;
            #pragma unroll
            for (int k = 0; k < 16; ++k){
                float4 v = Sr[c8 + k*8];
                s += expf(v.x-m) + expf(v.y-m) + expf(v.z-m) + expf(v.w-m);
            }
            s += __shfl_xor(s, 1); s += __shfl_xor(s, 2); s += __shfl_xor(s, 4);
            if (c8 == 0){ rowm[r] = m; rowi[r] = 1.f/s; }
        }
        __syncthreads();
        int tx = t & 15, ty = t >> 4;        // 16 row-pairs x 16 col-quads
        float4 acc0 = {0,0,0,0}, acc1 = {0,0,0,0};
        for (int k0 = 0; k0 < 512; k0 += 32){
            __syncthreads();
            {   // stage P chunk with exp applied on the fly
                int row = t >> 3, c4 = t & 7;
                float m = rowm[row], iv = rowi[row];
                float4 v = *(const float4*)(S + (i0+row)*512 + k0 + c4*4);
                As[(c4*4+0)*68 + row] = expf(v.x - m)*iv;
                As[(c4*4+1)*68 + row] = expf(v.y - m)*iv;
                As[(c4*4+2)*68 + row] = expf(v.z - m)*iv;
                As[(c4*4+3)*68 + row] = expf(v.w - m)*iv;
            }
            #pragma unroll
            for (int half = 0; half < 2; ++half){
                int idx = half*256 + t;
                int kkr = idx >> 4, c4 = idx & 15;
                *(float4*)(Bs + kkr*68 + c4*4) = *(const float4*)(VW + (k0+kkr)*256 + d0 + c4*4);
            }
            __syncthreads();
            #pragma unroll
            for (int kk = 0; kk < 32; ++kk){
                float2 a = *(const float2*)(As + kk*68 + ty*2);
                float4 b = *(const float4*)(Bs + kk*68 + tx*4);
                acc0.x += a.x*b.x; acc0.y += a.x*b.y; acc0.z += a.x*b.z; acc0.w += a.x*b.w;
                acc1.x += a.y*b.x; acc1.y += a.y*b.y; acc1.z += a.y*b.z; acc1.w += a.y*b.w;
            }
        }
        float4 bb = *(const float4*)(opb + d0 + tx*4);
        float4 o0, o1;
        o0.x = acc0.x+bb.x; o0.y = acc0.y+bb.y; o0.z = acc0.z+bb.z; o0.w = acc0.w+bb.w;
        o1.x = acc1.x+bb.x; o1.y = acc1.y+bb.y; o1.z = acc1.z+bb.z; o1.w = acc1.w+bb.w;
        *(float4*)(h + (i0+ty*2  )*256 + d0 + tx*4) = o0;
        *(float4*)(h + (i0+ty*2+1)*256 + d0 + tx*4) = o1;
    } else {
        stream_unit(1024 + (bid - 64), hid, vw2, partial, red, t);
    }
}

// ---- K3: grid 512. A/B projections; block 511 also finishes the value head ----
__global__ __launch_bounds__(256, 2) void k_s3(
        const float* __restrict__ hin, const float* __restrict__ w2,
        const float* __restrict__ b2, const float* __restrict__ partial,
        const float* __restrict__ vb, const float* __restrict__ v3w,
        const float* __restrict__ v3b, float* __restrict__ A,
        float* __restrict__ B, float* __restrict__ value)
{
    __shared__ float lin[2048];
    __shared__ float redv[4];
    int bid = blockIdx.x, t = threadIdx.x;
    if (bid == 511){
        float s = vb[t];
        #pragma unroll
        for (int c = 0; c < 8; ++c) s += partial[t*8 + c];
        s = fmaxf(s, 0.f) * v3w[t];
        for (int off = 32; off; off >>= 1) s += __shfl_xor(s, off);
        int lane = t & 63, wid = t >> 6;
        if (lane == 0) redv[wid] = s;
        __syncthreads();
        if (t == 0) value[0] = redv[0]+redv[1]+redv[2]+redv[3] + v3b[0];
        __syncthreads();
    }
    int at = bid >> 3, ot = bid & 7;
    const float4* in4 = (const float4*)(hin + at*8*HIDD);
    ((float4*)lin)[t]       = in4[t];
    ((float4*)lin)[t + 256] = in4[t + 256];
    __syncthreads();
    int ol = t & 63, g = t >> 6;
    int o2 = ot*64 + ol;                   // 0..511
    bool isA = o2 < HIDD;
    int o = isA ? o2 : o2 - HIDD;
    const float4* w4 = (const float4*)(w2 + o*512 + (isA ? 0 : HIDD));
    const float4* la4 = (const float4*)(lin + (g*2)*HIDD);
    const float4* lb4 = (const float4*)(lin + (g*2+1)*HIDD);
    float4 acc0 = {0,0,0,0}, acc1 = {0,0,0,0};
    #pragma unroll 8
    for (int c = 0; c < HIDD/4; ++c){
        float4 wv = w4[c];
        fma4(acc0, la4[c], wv);
        fma4(acc1, lb4[c], wv);
    }
    int a0 = at*8 + g*2;
    float* dst = isA ? A : B;
    float bb = isA ? b2[o] : 0.f;          // fold fc2_b into A
    dst[a0*HIDD + o]     = hsum(acc0) + bb;
    dst[(a0+1)*HIDD + o] = hsum(acc1) + bb;
}

// ---- K4: grid 512. pairs, 528 triangular tiles ----
__global__ __launch_bounds__(256, 2) void k_s4(
        const float* __restrict__ A, const float* __restrict__ B,
        const float* __restrict__ w3, const float* __restrict__ b3,
        const float* __restrict__ value, float* __restrict__ out)
{
    __shared__ float la[4160];             // 16*260
    __shared__ float lb[4160];
    __shared__ float lw[256];
    int bid = blockIdx.x, t = threadIdx.x;
    float val = value[0];
    float bd  = b3[0] - b3[1];
    for (int tile = bid; tile < 528; tile += 512){
        int rem = tile, ti = 0;
        while (rem >= 32 - ti){ rem -= 32 - ti; ++ti; }
        int tj = ti + rem;                 // ti <= tj guaranteed
        __syncthreads();
        #pragma unroll
        for (int l = 0; l < 4; ++l){
            int idx = l*256 + t;
            int r = idx >> 6, c4 = idx & 63;
            ((float4*)la)[r*65 + c4] = ((const float4*)A)[(ti*16 + r)*64 + c4];
            ((float4*)lb)[r*65 + c4] = ((const float4*)B)[(tj*16 + r)*64 + c4];
        }
        lw[t] = w3[t] - w3[256 + t];       // fc3_w[0]-fc3_w[1]
        __syncthreads();
        int il = t >> 4, jl = t & 15;
        int i = ti*16 + il, j = tj*16 + jl;
        if (j > i){
            const float4* a4 = (const float4*)(la + il*260);
            const float4* b4 = (const float4*)(lb + jl*260);
            const float4* w4 = (const float4*)lw;
            float4 acc = {0,0,0,0};
            #pragma unroll 8
            for (int c = 0; c < 64; ++c){
                float4 aa = a4[c], bb = b4[c], wv = w4[c];
                acc.x += fmaxf(aa.x + bb.x, 0.f)*wv.x;
                acc.y += fmaxf(aa.y + bb.y, 0.f)*wv.y;
                acc.z += fmaxf(aa.z + bb.z, 0.f)*wv.z;
                acc.w += fmaxf(aa.w + bb.w, 0.f)*wv.w;
            }
            float z = hsum(acc) + bd;
            float o0 = 1.f/(1.f + expf(-z));
            int p = i*511 - (i*(i-1))/2 + (j - i - 1);
            out[3*p]   = o0;
            out[3*p+1] = 1.f - o0;
            out[3*p+2] = val;
        }
    }
}

extern "C" void kernel_launch(void* const* d_in, const int* in_sizes, int n_in,
                              void* d_out, int out_size, void* d_ws, size_t ws_size,
                              hipStream_t stream){
    const float* inputs = (const float*)d_in[0];
    const float* fc1_w  = (const float*)d_in[1];
    const float* fc1_b  = (const float*)d_in[2];
    const float* inp_w  = (const float*)d_in[3];
    const float* inp_b  = (const float*)d_in[4];
    const float* outp_w = (const float*)d_in[5];
    const float* outp_b = (const float*)d_in[6];
    const float* fc2_w  = (const float*)d_in[7];
    const float* fc2_b  = (const float*)d_in[8];
    const float* fc3_w  = (const float*)d_in[9];
    const float* fc3_b  = (const float*)d_in[10];
    const float* vfc2_w = (const float*)d_in[11];
    const float* vfc2_b = (const float*)d_in[12];
    const float* vfc3_w = (const float*)d_in[13];
    const float* vfc3_b = (const float*)d_in[14];
    float* out = (float*)d_out;
    float* ws  = (float*)d_ws;
    // ws layout (floats)
    float* hid     = ws;              // 512*256
    float* qkv     = ws + 131072;     // 512*768
    float* S       = ws + 524288;     // 512*512 (raw scores; softmax fused downstream)
    float* VW      = ws + 786432;     // 512*256
    float* h       = ws + 917504;     // 512*256
    float* A       = ws + 1048576;    // 512*256
    float* B       = ws + 1179648;    // 512*256
    float* partial = ws + 1310720;    // 256*8
    float* value   = ws + 1312768;    // 1

    k_embed<<<dim3(512),  256, 0, stream>>>(inputs, fc1_w, fc1_b, inp_w, inp_b, hid, qkv);
    k_s1   <<<dim3(1120), 256, 0, stream>>>(qkv, outp_w, hid, vfc2_w, S, VW, partial);
    k_s2   <<<dim3(1088), 256, 0, stream>>>(S, VW, outp_b, hid, vfc2_w, h, partial);
    k_s3   <<<dim3(512),  256, 0, stream>>>(h, fc2_w, fc2_b, partial, vfc2_b, vfc3_w, vfc3_b, A, B, value);
    k_s4   <<<dim3(512),  256, 0, stream>>>(A, B, fc3_w, fc3_b, value, out);
}